// Round 7
// baseline (73389.062 us; speedup 1.0000x reference)
//
#include <hip/hip_runtime.h>
#include <hip/hip_bf16.h>

#define HH 20
#define TSTEPS 256
#define FF 64
#define BLK 128

__device__ __forceinline__ float fast_sigm(float x) {
    float e = __expf(-x);                          // [0, inf)
    return __builtin_amdgcn_rcpf(1.0f + e);        // rcp(inf) = 0, safe
}
__device__ __forceinline__ float fast_tanh(float x) {
    // tanh(x) = 1 - 2/(1 + e^{2x}); e^{2x}->inf => 1, ->0 => -1. No overflow.
    float e = __expf(2.0f * x);
    return 1.0f - 2.0f * __builtin_amdgcn_rcpf(1.0f + e);
}

// One thread per batch element. FULLY UNROLLED step body:
//  - every weight index is a compile-time constant -> guaranteed s_load
//    (imm offset off kernel-arg base), zero per-MAC address VALU
//  - h1/h2/c1/c2 statically indexed -> pure VGPR, ZERO LDS
//  - occupancy: VGPR-capped, __launch_bounds__(128,3) targets 3 waves/SIMD
__global__ __launch_bounds__(BLK, 3) void lstm_fused(
    const float* __restrict__ diag,
    const float* __restrict__ Wih1,                 // [80] (in_dim = 1)
    const float* __restrict__ Whh1,                 // [80][20] row-major
    const float* __restrict__ bih1, const float* __restrict__ bhh1,
    const float* __restrict__ Wih2,                 // [80][20]
    const float* __restrict__ Whh2,                 // [80][20]
    const float* __restrict__ bih2, const float* __restrict__ bhh2,
    const float* __restrict__ W1,  const float* __restrict__ b1,   // [64][20], [64]
    const float* __restrict__ W2,  const float* __restrict__ b2,   // [64], [1]
    float* __restrict__ out, int Btot)
{
    const int tid = threadIdx.x;
    const int b = blockIdx.x * BLK + tid;
    if (b >= Btot) return;

    float h1[HH], h2[HH], c1[HH], c2[HH];
    #pragma unroll
    for (int k = 0; k < HH; ++k) { h1[k] = 0.0f; h2[k] = 0.0f; c1[k] = 0.0f; c2[k] = 0.0f; }

    const float* __restrict__ xr = diag + (long long)b * TSTEPS;
    float x = xr[0];

    #pragma unroll 1
    for (int t = 0; t < TSTEPS; ++t) {
        float xnext = xr[(t + 1) & (TSTEPS - 1)];   // prefetch (wraps; unused at end)

        // ================= layer 1 =================
        float h1n[HH];
        #pragma unroll
        for (int u = 0; u < HH; ++u) {
            float zi = fmaf(x, Wih1[u         ], bih1[u         ] + bhh1[u         ]);
            float zf = fmaf(x, Wih1[u +     HH], bih1[u +     HH] + bhh1[u +     HH]);
            float zg = fmaf(x, Wih1[u + 2 * HH], bih1[u + 2 * HH] + bhh1[u + 2 * HH]);
            float zo = fmaf(x, Wih1[u + 3 * HH], bih1[u + 3 * HH] + bhh1[u + 3 * HH]);
            #pragma unroll
            for (int k = 0; k < HH; ++k) {
                float hk = h1[k];
                zi = fmaf(hk, Whh1[(u         ) * HH + k], zi);
                zf = fmaf(hk, Whh1[(u +     HH) * HH + k], zf);
                zg = fmaf(hk, Whh1[(u + 2 * HH) * HH + k], zg);
                zo = fmaf(hk, Whh1[(u + 3 * HH) * HH + k], zo);
            }
            float cn = fast_sigm(zf) * c1[u] + fast_sigm(zi) * fast_tanh(zg);
            c1[u] = cn;
            h1n[u] = fast_sigm(zo) * fast_tanh(cn);
        }

        // ================= layer 2 =================
        float h2n[HH];
        #pragma unroll
        for (int u = 0; u < HH; ++u) {
            float zi = bih2[u         ] + bhh2[u         ];
            float zf = bih2[u +     HH] + bhh2[u +     HH];
            float zg = bih2[u + 2 * HH] + bhh2[u + 2 * HH];
            float zo = bih2[u + 3 * HH] + bhh2[u + 3 * HH];
            #pragma unroll
            for (int k = 0; k < HH; ++k) {
                float a  = h1n[k];
                float bb = h2[k];
                zi = fmaf(a, Wih2[(u         ) * HH + k], zi);
                zf = fmaf(a, Wih2[(u +     HH) * HH + k], zf);
                zg = fmaf(a, Wih2[(u + 2 * HH) * HH + k], zg);
                zo = fmaf(a, Wih2[(u + 3 * HH) * HH + k], zo);
                zi = fmaf(bb, Whh2[(u         ) * HH + k], zi);
                zf = fmaf(bb, Whh2[(u +     HH) * HH + k], zf);
                zg = fmaf(bb, Whh2[(u + 2 * HH) * HH + k], zg);
                zo = fmaf(bb, Whh2[(u + 3 * HH) * HH + k], zo);
            }
            float cn = fast_sigm(zf) * c2[u] + fast_sigm(zi) * fast_tanh(zg);
            c2[u] = cn;
            h2n[u] = fast_sigm(zo) * fast_tanh(cn);
        }

        #pragma unroll
        for (int k = 0; k < HH; ++k) { h1[k] = h1n[k]; h2[k] = h2n[k]; }

        x = xnext;
    }

    // ---- head: relu(h2 @ W1^T + b1) -> relu(. @ W2^T + b2) ----
    float y2 = b2[0];
    #pragma unroll 1
    for (int j = 0; j < FF; ++j) {
        float a = b1[j];
        const float* __restrict__ wr = W1 + j * HH;
        #pragma unroll
        for (int k = 0; k < HH; ++k)
            a = fmaf(h2[k], wr[k], a);
        a = fmaxf(a, 0.0f);
        y2 = fmaf(a, W2[j], y2);
    }
    out[b] = fmaxf(y2, 0.0f);      // fp32 output, per reference dtype
}

extern "C" void kernel_launch(void* const* d_in, const int* in_sizes, int n_in,
                              void* d_out, int out_size, void* d_ws, size_t ws_size,
                              hipStream_t stream)
{
    (void)n_in; (void)ws_size; (void)out_size; (void)d_ws;
    const float* diag = (const float*)d_in[0];
    const float* Wih1 = (const float*)d_in[1];
    const float* Whh1 = (const float*)d_in[2];
    const float* bih1 = (const float*)d_in[3];
    const float* bhh1 = (const float*)d_in[4];
    const float* Wih2 = (const float*)d_in[5];
    const float* Whh2 = (const float*)d_in[6];
    const float* bih2 = (const float*)d_in[7];
    const float* bhh2 = (const float*)d_in[8];
    const float* W1   = (const float*)d_in[9];
    const float* b1   = (const float*)d_in[10];
    const float* W2   = (const float*)d_in[11];
    const float* b2   = (const float*)d_in[12];

    const int Btot = in_sizes[0] / TSTEPS;   // 131072

    lstm_fused<<<(Btot + BLK - 1) / BLK, BLK, 0, stream>>>(
        diag, Wih1, Whh1, bih1, bhh1,
        Wih2, Whh2, bih2, bhh2,
        W1, b1, W2, b2, (float*)d_out, Btot);
}